// Round 1
// baseline (801.881 us; speedup 1.0000x reference)
//
#include <hip/hip_runtime.h>
#include <stdint.h>

// Problem constants (fixed by the reference setup_inputs):
#define M_DIM 4096
#define N_DIM 8192   // O
#define K_DIM 8192   // I
#define NB    256    // K/32 Q4_0 blocks per row

#define BM 256
#define BN 256
#define BK 64

typedef __attribute__((ext_vector_type(8)))  __bf16 bf16x8;
typedef __attribute__((ext_vector_type(16))) float  floatx16;
typedef __attribute__((ext_vector_type(4)))  unsigned short ushort4v;
typedef __attribute__((ext_vector_type(8)))  unsigned short ushort8;

__device__ __forceinline__ unsigned short f32_to_bf16_rne(float f) {
    union { float f; unsigned int u; } v; v.f = f;
    unsigned int u = v.u;
    u += 0x7FFFu + ((u >> 16) & 1u);
    return (unsigned short)(u >> 16);
}

// ---- dequant: qweight[O,NB,16] int32-bytes + scales[O,NB] -> W bf16 [N,K] ----
__global__ __launch_bounds__(256) void dequant_w(const int* __restrict__ q,
                                                 const float* __restrict__ sc,
                                                 unsigned short* __restrict__ w) {
    const int tid = blockIdx.x * 256 + threadIdx.x;   // 0 .. O*NB*4-1
    int4 v = ((const int4*)q)[tid];
    const int blk = tid >> 2;      // Q4_0 block index (o*NB + b)
    const int s   = tid & 3;       // 4-byte sub-chunk within block
    const float scale = sc[blk];
    int by[4] = { v.x, v.y, v.z, v.w };
    ushort4v lo, hi;
#pragma unroll
    for (int j = 0; j < 4; ++j) {
        lo[j] = f32_to_bf16_rne((float)((by[j] & 0xF) - 8) * scale);
        hi[j] = f32_to_bf16_rne((float)(((by[j] >> 4) & 0xF) - 8) * scale);
    }
    unsigned short* base = w + (size_t)blk * 32 + s * 4;
    *(ushort4v*)(base)      = lo;
    *(ushort4v*)(base + 16) = hi;
}

// ---------------- x fp32 -> bf16 ----------------
__global__ __launch_bounds__(256) void convert_x(const float* __restrict__ x,
                                                 unsigned short* __restrict__ xb) {
    size_t idx = ((size_t)blockIdx.x * 256 + threadIdx.x) * 8;
    float4 f0 = *(const float4*)(x + idx);
    float4 f1 = *(const float4*)(x + idx + 4);
    ushort8 o;
    o[0] = f32_to_bf16_rne(f0.x); o[1] = f32_to_bf16_rne(f0.y);
    o[2] = f32_to_bf16_rne(f0.z); o[3] = f32_to_bf16_rne(f0.w);
    o[4] = f32_to_bf16_rne(f1.x); o[5] = f32_to_bf16_rne(f1.y);
    o[6] = f32_to_bf16_rne(f1.z); o[7] = f32_to_bf16_rne(f1.w);
    *(ushort8*)(xb + idx) = o;
}

// =====================================================================
// GEMM: C[M,N] = A[M,K] * B[N,K]^T + bias  — 256x256 tile, 8-phase schedule
// 8 waves (2M x 4N), wave tile 128x64 = 4x2 frags of 32x32, BK=64.
// LDS: 2 tile buffers (buf0 = even K-tiles, buf1 = odd), 128 KiB total.
// Per 2 K-tiles: 8 phases; each phase = {ds_read subtile | stage 1 half-tile
// (2 global_load_lds) | s_barrier | lgkmcnt(0) | setprio(1) 8xMFMA setprio(0)
// | [vmcnt(4) at ph4/ph8] | s_barrier}.
// Stage plan (iteration i, tiles t0=2i in buf0 / t0+1 in buf1):
//   ph1: buf1.A0(t0+1)  ph2: buf1.A1(t0+1)  ph3: buf0.B0(t0+2) ph4: buf0.B1(t0+2)
//   ph5: buf0.A0(t0+2)  ph6: buf0.A1(t0+2)  ph7: buf1.B0(t0+3) ph8: buf1.B1(t0+3)
// Hazard ledger: each staged region's last reader finished >=1 barrier before
// the stage issues (buf0.B read ph1-2, staged ph3-4; buf0.A read ph1,3, staged
// ph5-6; buf1 symmetric). vmcnt(4)@ph4 retires buf1 tile t0+1 (last half ph2 +
// 2 halves ph3/ph4 outstanding = 4 loads); vmcnt(4)@ph8 retires buf0 tile t0+2.
// Swizzle: LDS slot s holds global 16B-slot s ^ f(row), f = (row^(row>>3))&7;
// achieved with linear LDS dest + pre-swizzled global source (rule #21).
// =====================================================================
__device__ __forceinline__ void load_lds16(const unsigned short* g, unsigned short* l) {
    __builtin_amdgcn_global_load_lds(
        (const __attribute__((address_space(1))) unsigned int*)(g),
        (__attribute__((address_space(3))) unsigned int*)(l),
        16, 0, 0);
}

__device__ __forceinline__ floatx16 mfma_op(bf16x8 a, bf16x8 b, floatx16 c) {
    return __builtin_amdgcn_mfma_f32_32x32x16_bf16(a, b, c, 0, 0, 0);
}

// slot select on read: global slot (kk*2+q5), LDS slot = global ^ f(row)
#define SL(kk, F) (((((kk) * 2) + q5) ^ (F)) * 8)

// one half-tile = 128 rows of one array = 2 global_load_lds per wave
#define STAGE_A(b, h, kb) do { \
    load_lds16(gA + (size_t)((h) * 128 +  0) * K_DIM + (kb) * BK, &lsA[b][((h) * 128 +  0 + wave * 8) * BK]); \
    load_lds16(gA + (size_t)((h) * 128 + 64) * K_DIM + (kb) * BK, &lsA[b][((h) * 128 + 64 + wave * 8) * BK]); \
} while (0)
#define STAGE_B(b, h, kb) do { \
    load_lds16(gB + (size_t)((h) * 128 +  0) * K_DIM + (kb) * BK, &lsB[b][((h) * 128 +  0 + wave * 8) * BK]); \
    load_lds16(gB + (size_t)((h) * 128 + 64) * K_DIM + (kb) * BK, &lsB[b][((h) * 128 + 64 + wave * 8) * BK]); \
} while (0)

#define PH_HEAD __builtin_amdgcn_s_barrier(); \
                asm volatile("s_waitcnt lgkmcnt(0)" ::: "memory"); \
                __builtin_amdgcn_s_setprio(1)
#define PH_TAIL __builtin_amdgcn_s_setprio(0)

// 4 phases of one K-tile held in buffer bb; S1..S4 = per-phase stage stmts.
#define TILE(bb, S1, S2, S3, S4, VMW) do { \
    /* phase a: read A-low + B0, mfma (fi 0,1 x fj 0) */ \
    _Pragma("unroll") for (int kk = 0; kk < 4; ++kk) { \
        aL[0][kk] = *(const bf16x8*)(&lsA[bb][aA0 + SL(kk, F0)]); \
        aL[1][kk] = *(const bf16x8*)(&lsA[bb][aA1 + SL(kk, F1)]); \
        b0[kk]    = *(const bf16x8*)(&lsB[bb][aB0 + SL(kk, F0)]); \
    } \
    S1; PH_HEAD; \
    _Pragma("unroll") for (int kk = 0; kk < 4; ++kk) { \
        acc[0][0] = mfma_op(aL[0][kk], b0[kk], acc[0][0]); \
        acc[1][0] = mfma_op(aL[1][kk], b0[kk], acc[1][0]); \
    } \
    PH_TAIL; __builtin_amdgcn_s_barrier(); \
    /* phase b: read B1, mfma (fi 0,1 x fj 1) */ \
    _Pragma("unroll") for (int kk = 0; kk < 4; ++kk) \
        b1[kk] = *(const bf16x8*)(&lsB[bb][aB1 + SL(kk, F1)]); \
    S2; PH_HEAD; \
    _Pragma("unroll") for (int kk = 0; kk < 4; ++kk) { \
        acc[0][1] = mfma_op(aL[0][kk], b1[kk], acc[0][1]); \
        acc[1][1] = mfma_op(aL[1][kk], b1[kk], acc[1][1]); \
    } \
    PH_TAIL; __builtin_amdgcn_s_barrier(); \
    /* phase c: read A-high, mfma (fi 2,3 x fj 0) */ \
    _Pragma("unroll") for (int kk = 0; kk < 4; ++kk) { \
        aH[0][kk] = *(const bf16x8*)(&lsA[bb][aA2 + SL(kk, F0)]); \
        aH[1][kk] = *(const bf16x8*)(&lsA[bb][aA3 + SL(kk, F1)]); \
    } \
    S3; PH_HEAD; \
    _Pragma("unroll") for (int kk = 0; kk < 4; ++kk) { \
        acc[2][0] = mfma_op(aH[0][kk], b0[kk], acc[2][0]); \
        acc[3][0] = mfma_op(aH[1][kk], b0[kk], acc[3][0]); \
    } \
    PH_TAIL; __builtin_amdgcn_s_barrier(); \
    /* phase d: no reads, mfma (fi 2,3 x fj 1), counted vmcnt */ \
    S4; __builtin_amdgcn_s_barrier(); __builtin_amdgcn_s_setprio(1); \
    _Pragma("unroll") for (int kk = 0; kk < 4; ++kk) { \
        acc[2][1] = mfma_op(aH[0][kk], b1[kk], acc[2][1]); \
        acc[3][1] = mfma_op(aH[1][kk], b1[kk], acc[3][1]); \
    } \
    __builtin_amdgcn_s_setprio(0); VMW; __builtin_amdgcn_s_barrier(); \
} while (0)

__global__ __launch_bounds__(512, 2) void gemm_bt(const unsigned short* __restrict__ A,
                                                  const unsigned short* __restrict__ B,
                                                  const float* __restrict__ bias,
                                                  float* __restrict__ C) {
    __shared__ unsigned short lsA[2][BM * BK];   // 2 x 32 KiB
    __shared__ unsigned short lsB[2][BN * BK];   // 2 x 32 KiB

    const int tid  = threadIdx.x;
    const int wave = tid >> 6;
    const int lane = tid & 63;
    const int wm = wave >> 2;   // 0..1 : 128-row stripe of M
    const int wn = wave & 3;    // 0..3 : 64-col stripe of N

    // XCD-bijective swizzle (512 wgs % 8 == 0): each XCD gets 64 consecutive
    // wgs = 2 full tile-rows -> concurrent blocks share one 4 MiB A-panel in L2.
    const int bid = blockIdx.x;
    const int wg  = (bid & 7) * 64 + (bid >> 3);
    const int m0 = (wg >> 5) * BM;   // 16 tile-rows
    const int n0 = (wg & 31) * BN;   // 32 tile-cols

    // ---- staging addresses ----
    // LDS row r = h*128 + t*64 + wave*8 + lrow, slot = l7s (linear dest).
    // f(r) = (r ^ (r>>3)) & 7 = lrow ^ wave  (h,t contribute multiples of 8).
    const int lrow = lane >> 3;
    const int l7s  = lane & 7;
    const int csrc = ((l7s ^ lrow ^ wave) & 7) * 8;   // pre-swizzled source column
    const unsigned short* gA = A + (size_t)(m0 + wave * 8 + lrow) * K_DIM + csrc;
    const unsigned short* gB = B + (size_t)(n0 + wave * 8 + lrow) * K_DIM + csrc;

    // ---- fragment read addresses (32x32x16: A[m=lane&31][k=(lane>>5)*8+j]) ----
    const int q5  = lane >> 5;
    const int r31 = lane & 31;
    const int l7  = lane & 7;
    const int rh  = r31 >> 3;
    const int aA0 = (wm * 128 +  0 + r31) * BK;
    const int aA1 = (wm * 128 + 32 + r31) * BK;
    const int aA2 = (wm * 128 + 64 + r31) * BK;
    const int aA3 = (wm * 128 + 96 + r31) * BK;
    const int aB0 = (wn * 64  +  0 + r31) * BK;
    const int aB1 = (wn * 64  + 32 + r31) * BK;
    const int F0  = l7 ^ (rh & 7);         // f(row) for frag rows fi even
    const int F1  = l7 ^ ((4 + rh) & 7);   // fi odd (fi*4 mod 8 cycles 0,4)

    floatx16 acc[4][2] = {};
    bf16x8 aL[2][4], aH[2][4], b0[4], b1[4];

    // ---- prologue: tile0 fully + tile1 B-halves; wait all but last 2 halves ----
    STAGE_B(0, 0, 0); STAGE_B(0, 1, 0);
    STAGE_A(0, 0, 0); STAGE_A(0, 1, 0);
    STAGE_B(1, 0, 1); STAGE_B(1, 1, 1);
    asm volatile("s_waitcnt vmcnt(4)" ::: "memory");
    __builtin_amdgcn_s_barrier();

    // ---- main loop: 63 iterations x 2 K-tiles; tail (tiles 126,127) peeled ----
    for (int i = 0; i < 63; ++i) {
        const int t0 = 2 * i;
        TILE(0, STAGE_A(1, 0, t0 + 1), STAGE_A(1, 1, t0 + 1),
                STAGE_B(0, 0, t0 + 2), STAGE_B(0, 1, t0 + 2),
                asm volatile("s_waitcnt vmcnt(4)" ::: "memory"));
        TILE(1, STAGE_A(0, 0, t0 + 2), STAGE_A(0, 1, t0 + 2),
                STAGE_B(1, 0, t0 + 3), STAGE_B(1, 1, t0 + 3),
                asm volatile("s_waitcnt vmcnt(4)" ::: "memory"));
    }
    TILE(0, STAGE_A(1, 0, 127), STAGE_A(1, 1, 127), (void)0, (void)0,
            asm volatile("s_waitcnt vmcnt(0)" ::: "memory"));
    TILE(1, (void)0, (void)0, (void)0, (void)0, (void)0);

    // ---- epilogue. 32x32 C/D: col = lane&31, row = (r&3) + 8*(r>>2) + 4*q5 ----
#pragma unroll
    for (int fj = 0; fj < 2; ++fj) {
        const int col = n0 + wn * 64 + fj * 32 + r31;
        const float bv = bias[col];
#pragma unroll
        for (int fi = 0; fi < 4; ++fi) {
            const int rowbase = m0 + wm * 128 + fi * 32 + q5 * 4;
#pragma unroll
            for (int r = 0; r < 16; ++r) {
                const int row = rowbase + (r & 3) + 8 * (r >> 2);
                C[(size_t)row * N_DIM + col] = acc[fi][fj][r] + bv;
            }
        }
    }
}

extern "C" void kernel_launch(void* const* d_in, const int* in_sizes, int n_in,
                              void* d_out, int out_size, void* d_ws, size_t ws_size,
                              hipStream_t stream) {
    (void)in_sizes; (void)n_in; (void)out_size; (void)ws_size;
    const float* x    = (const float*)d_in[0];
    const int*   qw   = (const int*)d_in[1];
    const float* sc   = (const float*)d_in[2];
    const float* bias = (const float*)d_in[3];
    float* out = (float*)d_out;

    unsigned short* Wb = (unsigned short*)d_ws;                                      // 128 MiB
    unsigned short* Xb = (unsigned short*)((char*)d_ws + (size_t)N_DIM * K_DIM * 2); // +64 MiB

    dequant_w<<<dim3((N_DIM * NB * 4) / 256), dim3(256), 0, stream>>>(qw, sc, Wb);
    convert_x<<<dim3((size_t)M_DIM * K_DIM / (256 * 8)), dim3(256), 0, stream>>>(x, Xb);
    gemm_bt<<<dim3((M_DIM / BM) * (N_DIM / BN)), dim3(512), 0, stream>>>(Xb, Wb, bias, out);
}